// Round 8
// baseline (17.758 us; speedup 1.0000x reference)
//
#include <hip/hip_runtime.h>
#include <math.h>

// StridedAttention, swapped-QK MFMA, QB=32 / 2-wave blocks for 2x block residency.
// Structure identical to the validated r5 kernel (3 barriers, V^T overlay post-QK).
// B=1, H=16, S=2048, D=64, window ±16 (33 local), stride 32 (64 strided)

typedef __attribute__((ext_vector_type(8))) short bf16x8;   // 8 bf16 = 4 VGPR
typedef __attribute__((ext_vector_type(4))) float f32x4;

constexpr int H = 16, S = 2048, D = 64, W = 16;
constexpr int QB    = 32;     // queries per block
constexpr int NLOC  = 64;     // local union rows (QB + 2W)
constexpr int NROWS = 128;    // 64 local + 64 strided
constexpr int NT    = 8;      // key tiles of 16
constexpr float S2 = 0.18033688011112042f;   // 0.125*log2(e); folded into Q staging

// LDS layout (ushort units); strides multiple of 8 ushort (16B) for b128.
constexpr int QSTR = 72;                  // 144 B rows
constexpr int VSTR = 136;                 // 272 B rows (128 slots + 8 pad)
constexpr int QHI  = 0;                   // Q hi [32][72]
constexpr int QLO  = QHI + QB * QSTR;     // 2304: Q lo [32][72]
constexpr int KB   = QLO + QB * QSTR;     // 4608: K bf16 [128][72]
constexpr int VTB  = 0;                   // overlay after barrier 2: V^T [64][136]
constexpr int LDS_U = KB + NROWS * QSTR;  // 13824 ushort = 27648 B -> 5 blocks/CU cap

__device__ __forceinline__ ushort f2bf(float x) {
    union { float f; unsigned u; } t; t.f = x;
    unsigned r = t.u + 0x7fffu + ((t.u >> 16) & 1u);   // RNE
    return (ushort)(r >> 16);
}
__device__ __forceinline__ float bf2f(ushort b) {
    union { float f; unsigned u; } t; t.u = ((unsigned)b) << 16;
    return t.f;
}
__device__ __forceinline__ unsigned pk2(float a, float b) {
    return (unsigned)f2bf(a) | ((unsigned)f2bf(b) << 16);
}
__device__ __forceinline__ bf16x8 cvt8(const float4& a, const float4& b) {
    union { bf16x8 v; unsigned u[4]; } r;
    r.u[0] = pk2(a.x, a.y); r.u[1] = pk2(a.z, a.w);
    r.u[2] = pk2(b.x, b.y); r.u[3] = pk2(b.z, b.w);
    return r.v;
}
__device__ __forceinline__ int rowpos(int r, int n0) {
    if (r < NLOC) {
        int p = n0 - W + r;               // clamped rows masked in softmax
        return p < 0 ? 0 : (p > S - 1 ? S - 1 : p);
    }
    return (r - NLOC) * 32;               // strided keys
}

__global__ __launch_bounds__(128, 2) void strided_attn_mfma(
    const float* __restrict__ q,
    const float* __restrict__ k,
    const float* __restrict__ v,
    float* __restrict__ out)
{
    __shared__ ushort lds[LDS_U];

    const int tid  = threadIdx.x;
    const int w    = tid >> 6;            // wave 0/1, owns 16 queries
    const int lane = tid & 63;
    const int c    = lane & 15;           // query column within wave's 16
    const int g    = lane >> 4;           // k-chunk
    // XCD-aware bijective swizzle (1024 % 8 == 0): each head's 64 blocks on one XCD
    const int bid  = blockIdx.x;
    const int swz  = (bid & 7) * 128 + (bid >> 3);
    const int h    = swz >> 6;
    const int n0   = (swz & 63) << 5;

    const float* __restrict__ qh = q + (size_t)(h * S) * D;
    const float* __restrict__ kh = k + (size_t)(h * S) * D;
    const float* __restrict__ vh = v + (size_t)(h * S) * D;

    // ---- V prefetch into regs (issue-early). 512 tasks: 2 rows x 8 dims each.
    float4 vreg[4][4];
#pragma unroll
    for (int tt = 0; tt < 4; ++tt) {
        const int tau = tid + (tt << 7);
        const int rp = tau & 63, ch = tau >> 6;
        const float* s0 = vh + (size_t)rowpos(2 * rp,     n0) * D + ch * 8;
        const float* s1 = vh + (size_t)rowpos(2 * rp + 1, n0) * D + ch * 8;
        vreg[tt][0] = *(const float4*)s0;
        vreg[tt][1] = *(const float4*)(s0 + 4);
        vreg[tt][2] = *(const float4*)s1;
        vreg[tt][3] = *(const float4*)(s1 + 4);
    }

    // ---- stage Q (hi/lo, pre-scaled by S2; 256 tasks) + K (bf16, 1024 tasks) ----
    for (int t = tid; t < 1280; t += 128) {
        if (t < 256) {
            const int row = t >> 3, ch = t & 7;
            const float* src = qh + (size_t)(n0 + row) * D + ch * 8;
            const float4 a = *(const float4*)src;
            const float4 b = *(const float4*)(src + 4);
            const float xs[8] = {a.x * S2, a.y * S2, a.z * S2, a.w * S2,
                                 b.x * S2, b.y * S2, b.z * S2, b.w * S2};
            union { bf16x8 v; ushort u[8]; } hi, lo;
#pragma unroll
            for (int j = 0; j < 8; ++j) {
                const ushort hb = f2bf(xs[j]);
                hi.u[j] = hb;
                lo.u[j] = f2bf(xs[j] - bf2f(hb));
            }
            *(bf16x8*)&lds[QHI + row * QSTR + ch * 8] = hi.v;
            *(bf16x8*)&lds[QLO + row * QSTR + ch * 8] = lo.v;
        } else {
            const int u = t - 256;
            const int row = u >> 3, ch = u & 7;
            const float* src = kh + (size_t)rowpos(row, n0) * D + ch * 8;
            const float4 a = *(const float4*)src;
            const float4 b = *(const float4*)(src + 4);
            *(bf16x8*)&lds[KB + row * QSTR + ch * 8] = cvt8(a, b);
        }
    }
    __syncthreads();   // barrier 1: Q/K staged

    // ---- QK^T swapped (S^T = K·Q^T): wave w, 16 queries x all 128 keys ----
    const int qb = w * 16;
    const int qi = qb + c;                // this lane's block-relative query
    const int nq = n0 + qi;
    const int qa = (qb + c) * QSTR + g * 8;
    const bf16x8 bQH0 = *(bf16x8*)&lds[QHI + qa];
    const bf16x8 bQH1 = *(bf16x8*)&lds[QHI + qa + 32];
    const bf16x8 bQL0 = *(bf16x8*)&lds[QLO + qa];
    const bf16x8 bQL1 = *(bf16x8*)&lds[QLO + qa + 32];

    f32x4 acc[NT];
#pragma unroll
    for (int t = 0; t < NT; ++t) acc[t] = (f32x4){0.f, 0.f, 0.f, 0.f};
#pragma unroll
    for (int t = 0; t < NT; ++t) {
        const int kb = KB + (t * 16 + c) * QSTR + g * 8;
        const bf16x8 a0 = *(bf16x8*)&lds[kb];
        const bf16x8 a1 = *(bf16x8*)&lds[kb + 32];
        f32x4 a4 = acc[t];
        a4 = __builtin_amdgcn_mfma_f32_16x16x32_bf16(a0, bQH0, a4, 0, 0, 0);
        a4 = __builtin_amdgcn_mfma_f32_16x16x32_bf16(a1, bQH1, a4, 0, 0, 0);
        a4 = __builtin_amdgcn_mfma_f32_16x16x32_bf16(a0, bQL0, a4, 0, 0, 0);
        a4 = __builtin_amdgcn_mfma_f32_16x16x32_bf16(a1, bQL1, a4, 0, 0, 0);
        acc[t] = a4;
    }

    // ---- softmax fully in-lane (exp2 domain; logits already scaled) ----
    float p[NT][4];
#pragma unroll
    for (int t = 0; t < 4; ++t) {        // local tiles: rows j = 16t+4g+i (0..63)
#pragma unroll
        for (int i = 0; i < 4; ++i) {
            const int j = t * 16 + 4 * g + i;
            const bool ok = ((unsigned)(j - qi) <= 32u) &&
                            ((unsigned)(n0 - W + j) < (unsigned)S);
            p[t][i] = ok ? acc[t][i] : -INFINITY;
        }
    }
    const bool us = nq > W;
#pragma unroll
    for (int t = 4; t < NT; ++t)
#pragma unroll
        for (int i = 0; i < 4; ++i)
            p[t][i] = us ? acc[t][i] : -INFINITY;

    float m = -INFINITY;
#pragma unroll
    for (int t = 0; t < NT; ++t)
#pragma unroll
        for (int i = 0; i < 4; ++i) m = fmaxf(m, p[t][i]);
    m = fmaxf(m, __shfl_xor(m, 16));
    m = fmaxf(m, __shfl_xor(m, 32));     // finite: self-key always valid

    float l = 0.f;
#pragma unroll
    for (int t = 0; t < NT; ++t)
#pragma unroll
        for (int i = 0; i < 4; ++i) { p[t][i] = exp2f(p[t][i] - m); l += p[t][i]; }
    l += __shfl_xor(l, 16);
    l += __shfl_xor(l, 32);
    const float inv = 1.0f / l;

    // ---- pack P into PV A-frags in-register (k-permutation shared with V^T) ----
    union { bf16x8 v; unsigned u[4]; } pa[4];
#pragma unroll
    for (int kt = 0; kt < 4; ++kt) {
        pa[kt].u[0] = pk2(p[2 * kt][0] * inv,     p[2 * kt][1] * inv);
        pa[kt].u[1] = pk2(p[2 * kt][2] * inv,     p[2 * kt][3] * inv);
        pa[kt].u[2] = pk2(p[2 * kt + 1][0] * inv, p[2 * kt + 1][1] * inv);
        pa[kt].u[3] = pk2(p[2 * kt + 1][2] * inv, p[2 * kt + 1][3] * inv);
    }

    __syncthreads();   // barrier 2: Q/K LDS dead -> V^T overlay safe

    // ---- write V^T at permuted slots: key 32kt+16u+4g2+jj -> slot 32kt+8g2+4u+jj
#pragma unroll
    for (int tt = 0; tt < 4; ++tt) {
        const int tau = tid + (tt << 7);
        const int rp = tau & 63, ch = tau >> 6;
        const float r0[8] = {vreg[tt][0].x, vreg[tt][0].y, vreg[tt][0].z, vreg[tt][0].w,
                             vreg[tt][1].x, vreg[tt][1].y, vreg[tt][1].z, vreg[tt][1].w};
        const float r1[8] = {vreg[tt][2].x, vreg[tt][2].y, vreg[tt][2].z, vreg[tt][2].w,
                             vreg[tt][3].x, vreg[tt][3].y, vreg[tt][3].z, vreg[tt][3].w};
        const int kk = 2 * rp;
        const int kt = kk >> 5, rem = kk & 31;
        const int slot = kt * 32 + ((rem >> 2) & 3) * 8 + (rem >> 4) * 4 + (rem & 3);
#pragma unroll
        for (int j = 0; j < 8; ++j)
            *(unsigned*)&lds[VTB + (ch * 8 + j) * VSTR + slot] = pk2(r0[j], r1[j]);
    }
    __syncthreads();   // barrier 3: V^T visible

    // ---- PV: o[q][d] = P(16x128) x V(128x64); A = pa (in-reg), B = V^T ----
    f32x4 o[4];
#pragma unroll
    for (int dt = 0; dt < 4; ++dt) o[dt] = (f32x4){0.f, 0.f, 0.f, 0.f};
#pragma unroll
    for (int kt = 0; kt < 4; ++kt) {
#pragma unroll
        for (int dt = 0; dt < 4; ++dt) {
            const bf16x8 vb = *(bf16x8*)&lds[VTB + (dt * 16 + c) * VSTR + kt * 32 + g * 8];
            o[dt] = __builtin_amdgcn_mfma_f32_16x16x32_bf16(pa[kt].v, vb, o[dt], 0, 0, 0);
        }
    }

    // ---- store (D row = query qb+4g+i, col c = dim within tile; P pre-normalized)
#pragma unroll
    for (int i = 0; i < 4; ++i) {
        const int n = n0 + qb + 4 * g + i;
        float* op = out + ((size_t)(h * S) + n) * D + c;
#pragma unroll
        for (int dt = 0; dt < 4; ++dt) op[dt * 16] = o[dt][i];
    }
}

extern "C" void kernel_launch(void* const* d_in, const int* in_sizes, int n_in,
                              void* d_out, int out_size, void* d_ws, size_t ws_size,
                              hipStream_t stream) {
    (void)in_sizes; (void)n_in; (void)d_ws; (void)ws_size; (void)out_size;
    const float* q = (const float*)d_in[0];
    const float* k = (const float*)d_in[1];
    const float* v = (const float*)d_in[2];
    float* out     = (float*)d_out;

    dim3 grid(H * (S / QB));   // 1024 blocks of 128 threads -> 4 resident/CU
    dim3 block(128);
    strided_attn_mfma<<<grid, block, 0, stream>>>(q, k, v, out);
}

// Round 9
// 16.460 us; speedup vs baseline: 1.0788x; 1.0788x over previous
//
#include <hip/hip_runtime.h>
#include <math.h>

// StridedAttention, swapped-QK MFMA, QB=128 / 8-wave blocks: minimal staging
// redundancy (1.75 rows/query). r5-validated 3-barrier skeleton; Q direct to regs.
// B=1, H=16, S=2048, D=64, window ±16 (33 local), stride 32 (64 strided)

typedef __attribute__((ext_vector_type(8))) short bf16x8;   // 8 bf16 = 4 VGPR
typedef __attribute__((ext_vector_type(4))) float f32x4;

constexpr int H = 16, S = 2048, D = 64, W = 16;
constexpr int QB    = 128;    // queries per block
constexpr int NLOC  = 160;    // local union rows (QB + 2W)
constexpr int NROWS = 224;    // 160 local + 64 strided
constexpr int NT    = 14;     // key tiles of 16
constexpr int NLT   = 10;     // local tiles (160/16)
constexpr float S2 = 0.18033688011112042f;   // 0.125*log2(e); folded into Q

// LDS (ushort units); strides multiple of 8 ushort (16B) for b128.
constexpr int KSTRIDE = 72;               // K row: 64 bf16 + 8 pad (144 B)
constexpr int VSTR    = 232;              // V^T row: 224 slots + 8 pad (464 B)
constexpr int KB      = 0;                // K bf16 [224][72]
constexpr int VTB     = 0;                // overlay after barrier 2: V^T [64][232]
constexpr int LDS_U   = NROWS * KSTRIDE;  // 16128 ushort = 32256 B (V^T 14848 fits)

__device__ __forceinline__ ushort f2bf(float x) {
    union { float f; unsigned u; } t; t.f = x;
    unsigned r = t.u + 0x7fffu + ((t.u >> 16) & 1u);   // RNE
    return (ushort)(r >> 16);
}
__device__ __forceinline__ float bf2f(ushort b) {
    union { float f; unsigned u; } t; t.u = ((unsigned)b) << 16;
    return t.f;
}
__device__ __forceinline__ unsigned pk2(float a, float b) {
    return (unsigned)f2bf(a) | ((unsigned)f2bf(b) << 16);
}
__device__ __forceinline__ bf16x8 cvt8(const float4& a, const float4& b) {
    union { bf16x8 v; unsigned u[4]; } r;
    r.u[0] = pk2(a.x, a.y); r.u[1] = pk2(a.z, a.w);
    r.u[2] = pk2(b.x, b.y); r.u[3] = pk2(b.z, b.w);
    return r.v;
}
__device__ __forceinline__ void cvt_hilo(const float4& a, const float4& b,
                                         bf16x8& hi, bf16x8& lo) {
    const float xs[8] = {a.x, a.y, a.z, a.w, b.x, b.y, b.z, b.w};
    union { bf16x8 v; ushort u[8]; } Hv, Lv;
#pragma unroll
    for (int j = 0; j < 8; ++j) {
        const ushort hb = f2bf(xs[j]);
        Hv.u[j] = hb;
        Lv.u[j] = f2bf(xs[j] - bf2f(hb));
    }
    hi = Hv.v; lo = Lv.v;
}
__device__ __forceinline__ int rowpos(int r, int n0) {
    if (r < NLOC) {
        int p = n0 - W + r;               // clamped rows masked in softmax
        return p < 0 ? 0 : (p > S - 1 ? S - 1 : p);
    }
    return (r - NLOC) * 32;               // strided keys
}

__global__ __launch_bounds__(512, 2) void strided_attn_mfma(
    const float* __restrict__ q,
    const float* __restrict__ k,
    const float* __restrict__ v,
    float* __restrict__ out)
{
    __shared__ ushort lds[LDS_U];

    const int tid  = threadIdx.x;
    const int w    = tid >> 6;            // wave 0..7, owns 16 queries
    const int lane = tid & 63;
    const int c    = lane & 15;           // query column within wave's 16
    const int g    = lane >> 4;           // k-chunk
    // XCD-aware bijective swizzle (256 % 8 == 0): 2 heads per XCD
    const int bid  = blockIdx.x;
    const int swz  = (bid & 7) * 32 + (bid >> 3);
    const int h    = swz >> 4;
    const int n0   = (swz & 15) << 7;

    const float* __restrict__ qh = q + (size_t)(h * S) * D;
    const float* __restrict__ kh = k + (size_t)(h * S) * D;
    const float* __restrict__ vh = v + (size_t)(h * S) * D;

    // ---- V prefetch into regs (issue-early). 896 tasks: 2 rows x 8 dims each.
    const int ntask = (tid < 384) ? 2 : 1;
    float4 vreg[2][4];
    int vrp[2], vch[2];
#pragma unroll
    for (int tt = 0; tt < 2; ++tt) {
        if (tt < ntask) {
            const int tau = tid + (tt << 9);
            const int rp = tau % 112, ch = tau / 112;
            vrp[tt] = rp; vch[tt] = ch;
            const float* s0 = vh + (size_t)rowpos(2 * rp,     n0) * D + ch * 8;
            const float* s1 = vh + (size_t)rowpos(2 * rp + 1, n0) * D + ch * 8;
            vreg[tt][0] = *(const float4*)s0;
            vreg[tt][1] = *(const float4*)(s0 + 4);
            vreg[tt][2] = *(const float4*)s1;
            vreg[tt][3] = *(const float4*)(s1 + 4);
        }
    }

    // ---- Q direct load (issue-early); S2 folded; hi/lo convert to B-frags ----
    const int qb = w * 16;
    const int qi = qb + c;                // this lane's block-relative query
    const int nq = n0 + qi;
    const float* qrow = qh + (size_t)(n0 + qb + c) * D;
    float4 qv00 = *(const float4*)(qrow + g * 8);
    float4 qv01 = *(const float4*)(qrow + g * 8 + 4);
    float4 qv10 = *(const float4*)(qrow + 32 + g * 8);
    float4 qv11 = *(const float4*)(qrow + 32 + g * 8 + 4);

    // ---- K staging (coalesced): 1792 tasks of 8 dims, 3.5 iters ----
    for (int t = tid; t < 1792; t += 512) {
        const int row = t >> 3, ch = t & 7;
        const float* src = kh + (size_t)rowpos(row, n0) * D + ch * 8;
        const float4 a = *(const float4*)src;
        const float4 b = *(const float4*)(src + 4);
        *(bf16x8*)&lds[KB + row * KSTRIDE + ch * 8] = cvt8(a, b);
    }

    // ---- Q frag convert with S2 pre-scale (overlaps staging latency) ----
    qv00.x *= S2; qv00.y *= S2; qv00.z *= S2; qv00.w *= S2;
    qv01.x *= S2; qv01.y *= S2; qv01.z *= S2; qv01.w *= S2;
    qv10.x *= S2; qv10.y *= S2; qv10.z *= S2; qv10.w *= S2;
    qv11.x *= S2; qv11.y *= S2; qv11.z *= S2; qv11.w *= S2;
    bf16x8 bQH0, bQL0, bQH1, bQL1;
    cvt_hilo(qv00, qv01, bQH0, bQL0);
    cvt_hilo(qv10, qv11, bQH1, bQL1);

    // ---- pack V to bf16 pairs (waits on V loads; overlapped with K staging) ----
    unsigned vpk[2][8];
#pragma unroll
    for (int tt = 0; tt < 2; ++tt) {
        if (tt < ntask) {
            const float r0[8] = {vreg[tt][0].x, vreg[tt][0].y, vreg[tt][0].z, vreg[tt][0].w,
                                 vreg[tt][1].x, vreg[tt][1].y, vreg[tt][1].z, vreg[tt][1].w};
            const float r1[8] = {vreg[tt][2].x, vreg[tt][2].y, vreg[tt][2].z, vreg[tt][2].w,
                                 vreg[tt][3].x, vreg[tt][3].y, vreg[tt][3].z, vreg[tt][3].w};
#pragma unroll
            for (int j = 0; j < 8; ++j) vpk[tt][j] = pk2(r0[j], r1[j]);
        }
    }
    __syncthreads();   // barrier 1: K staged

    // ---- QK^T swapped (S^T = K·Q^T): wave w, 16 queries x all 224 keys ----
    f32x4 acc[NT];
#pragma unroll
    for (int t = 0; t < NT; ++t) acc[t] = (f32x4){0.f, 0.f, 0.f, 0.f};
#pragma unroll
    for (int t = 0; t < NT; ++t) {
        const int kb = KB + (t * 16 + c) * KSTRIDE + g * 8;
        const bf16x8 a0 = *(bf16x8*)&lds[kb];
        const bf16x8 a1 = *(bf16x8*)&lds[kb + 32];
        f32x4 a4 = acc[t];
        a4 = __builtin_amdgcn_mfma_f32_16x16x32_bf16(a0, bQH0, a4, 0, 0, 0);
        a4 = __builtin_amdgcn_mfma_f32_16x16x32_bf16(a1, bQH1, a4, 0, 0, 0);
        a4 = __builtin_amdgcn_mfma_f32_16x16x32_bf16(a0, bQL0, a4, 0, 0, 0);
        a4 = __builtin_amdgcn_mfma_f32_16x16x32_bf16(a1, bQL1, a4, 0, 0, 0);
        acc[t] = a4;
    }

    // ---- softmax in place in acc (exp2 domain; logits pre-scaled via Q) ----
#pragma unroll
    for (int t = 0; t < NLT; ++t) {
#pragma unroll
        for (int i = 0; i < 4; ++i) {
            const int j = t * 16 + 4 * g + i;
            const bool ok = ((unsigned)(j - qi) <= 32u) &&
                            ((unsigned)(n0 - W + j) < (unsigned)S);
            acc[t][i] = ok ? acc[t][i] : -INFINITY;
        }
    }
    const bool us = nq > W;
#pragma unroll
    for (int t = NLT; t < NT; ++t)
#pragma unroll
        for (int i = 0; i < 4; ++i)
            acc[t][i] = us ? acc[t][i] : -INFINITY;

    float m = -INFINITY;
#pragma unroll
    for (int t = 0; t < NT; ++t)
#pragma unroll
        for (int i = 0; i < 4; ++i) m = fmaxf(m, acc[t][i]);
    m = fmaxf(m, __shfl_xor(m, 16));
    m = fmaxf(m, __shfl_xor(m, 32));     // finite: self-key always valid

    float l = 0.f;
#pragma unroll
    for (int t = 0; t < NT; ++t)
#pragma unroll
        for (int i = 0; i < 4; ++i) { acc[t][i] = exp2f(acc[t][i] - m); l += acc[t][i]; }
    l += __shfl_xor(l, 16);
    l += __shfl_xor(l, 32);
    const float inv = 1.0f / l;

    // ---- pack P into PV A-frags in-register (k-permutation shared with V^T) ----
    union { bf16x8 v; unsigned u[4]; } pa[7];
#pragma unroll
    for (int kt = 0; kt < 7; ++kt) {
        pa[kt].u[0] = pk2(acc[2 * kt][0] * inv,     acc[2 * kt][1] * inv);
        pa[kt].u[1] = pk2(acc[2 * kt][2] * inv,     acc[2 * kt][3] * inv);
        pa[kt].u[2] = pk2(acc[2 * kt + 1][0] * inv, acc[2 * kt + 1][1] * inv);
        pa[kt].u[3] = pk2(acc[2 * kt + 1][2] * inv, acc[2 * kt + 1][3] * inv);
    }

    __syncthreads();   // barrier 2: K LDS dead -> V^T overlay safe

    // ---- write V^T at permuted slots: key 32kt+16u+4g2+jj -> slot 32kt+8g2+4u+jj
#pragma unroll
    for (int tt = 0; tt < 2; ++tt) {
        if (tt < ntask) {
            const int rp = vrp[tt], ch = vch[tt];
            const int kk = 2 * rp;
            const int kt = kk >> 5, rem = kk & 31;
            const int slot = kt * 32 + ((rem >> 2) & 3) * 8 + (rem >> 4) * 4 + (rem & 3);
#pragma unroll
            for (int j = 0; j < 8; ++j)
                *(unsigned*)&lds[VTB + (ch * 8 + j) * VSTR + slot] = vpk[tt][j];
        }
    }
    __syncthreads();   // barrier 3: V^T visible

    // ---- PV: o[q][d] = P(16x224) x V(224x64); A = pa (in-reg), B = V^T ----
    f32x4 o[4];
#pragma unroll
    for (int dt = 0; dt < 4; ++dt) o[dt] = (f32x4){0.f, 0.f, 0.f, 0.f};
#pragma unroll
    for (int kt = 0; kt < 7; ++kt) {
#pragma unroll
        for (int dt = 0; dt < 4; ++dt) {
            const bf16x8 vb = *(bf16x8*)&lds[VTB + (dt * 16 + c) * VSTR + kt * 32 + g * 8];
            o[dt] = __builtin_amdgcn_mfma_f32_16x16x32_bf16(pa[kt].v, vb, o[dt], 0, 0, 0);
        }
    }

    // ---- store (D row = query qb+4g+i, col c = dim within tile; P pre-normalized)
#pragma unroll
    for (int i = 0; i < 4; ++i) {
        const int n = n0 + qb + 4 * g + i;
        float* op = out + ((size_t)(h * S) + n) * D + c;
#pragma unroll
        for (int dt = 0; dt < 4; ++dt) op[dt * 16] = o[dt][i];
    }
}

extern "C" void kernel_launch(void* const* d_in, const int* in_sizes, int n_in,
                              void* d_out, int out_size, void* d_ws, size_t ws_size,
                              hipStream_t stream) {
    (void)in_sizes; (void)n_in; (void)d_ws; (void)ws_size; (void)out_size;
    const float* q = (const float*)d_in[0];
    const float* k = (const float*)d_in[1];
    const float* v = (const float*)d_in[2];
    float* out     = (float*)d_out;

    dim3 grid(H * (S / QB));   // 256 blocks of 512 threads -> 1 per CU
    dim3 block(512);
    strided_attn_mfma<<<grid, block, 0, stream>>>(q, k, v, out);
}